// Round 7
// baseline (1647.372 us; speedup 1.0000x reference)
//
#include <hip/hip_runtime.h>

#define NN    4096
#define BIGF  1e8f
// Scaled domain: R' = R * K2, K2 = (1/GAMMA)*log2(e).
// softmin'(a,b,c) = m - log2(exp2(m-a)+exp2(m-b)+exp2(m-c)); loss = R'/K2.
#define SQK2f 12.0112245225638540f    // sqrt(K2)
#define BIGK  1.4426950408889634e10f  // 1e8 * K2
#define IK2f  0.00693147180559945309f // 1/K2 = GAMMA*ln2
#define NBLK  16       // blocks of 256 rows: X = rows 0..127, Y = rows 128..255 (per block)
#define NCI   136      // chunks of 32 steps: s = 0..4351
#define OUTS  4351     // block15 Y lane63 col 4095 at s = 4095 + 256
#define YLAG  130      // Y lane l col = s - YLAG - 2l (even: keeps float2 loads aligned)
#define SENTU 0xFFFFFFFFu   // NaN sentinel: DP values are never NaN

// ---------------- fallback: single-block diagonal kernel (verified r1) ----------------
__global__ __launch_bounds__(1024) void dilate_sdtw(const float* __restrict__ pred,
                                                    const float* __restrict__ target,
                                                    float* __restrict__ out) {
    __shared__ float t_s[NN];
    __shared__ float p_s[NN];
    __shared__ float bufA[NN];
    __shared__ float bufB[NN];
    __shared__ float bufC[NN];
    const int tid = threadIdx.x;
    for (int i = tid; i < NN; i += 1024) {
        t_s[i] = target[i]; p_s[i] = pred[i];
        bufA[i] = BIGF; bufB[i] = BIGF; bufC[i] = BIGF;
    }
    __syncthreads();
    float* r2 = bufA; float* r1 = bufB; float* rn = bufC;
    for (int k = 0; k < 2 * NN - 1; ++k) {
        int ilo = k - (NN - 1); if (ilo < 0) ilo = 0;
        int ihi = (k < NN - 1) ? k : (NN - 1);
        for (int i = ilo + tid; i <= ihi; i += 1024) {
            const int j = k - i;
            float diff = t_s[i] - p_s[j];
            float d = diff * diff;
            float a = (i >= 1 && j >= 1) ? r2[i - 1] : ((k == 0) ? 0.0f : BIGF);
            float b = (i >= 1) ? r1[i - 1] : BIGF;
            float c = (j >= 1) ? r1[i] : BIGF;
            float m = fminf(a, fminf(b, c));
            float s = __expf((m - a) * 100.0f) + __expf((m - b) * 100.0f) + __expf((m - c) * 100.0f);
            rn[i] = d + m - 0.01f * __logf(s);
        }
        __syncthreads();
        float* tmp = r2; r2 = r1; r1 = rn; rn = tmp;
    }
    if (tid == 0) out[0] = r1[NN - 1];
}

// ------- dual sub-stripe (ILP=2) lane-systolic, stagger-2, K2-scaled, fence-free -------

__device__ __forceinline__ float softmin3s(float a, float b, float c) {
    float m = fminf(a, fminf(b, c));
    float e = __builtin_amdgcn_exp2f(m - a)
            + __builtin_amdgcn_exp2f(m - b)
            + __builtin_amdgcn_exp2f(m - c);
    return m - __builtin_amdgcn_logf(e);   // logf builtin = log2
}

__device__ __forceinline__ void bput(float* p, float v) {
    __hip_atomic_store((unsigned int*)p, __float_as_uint(v),
                       __ATOMIC_RELAXED, __HIP_MEMORY_SCOPE_AGENT);
}
__device__ __forceinline__ unsigned int bgetu(const float* p) {
    return __hip_atomic_load((const unsigned int*)p,
                             __ATOMIC_RELAXED, __HIP_MEMORY_SCOPE_AGENT);
}

__device__ __forceinline__ void upoll(const float* src, float* dst) {
    bool ready;
    do {
        ready = true;
#pragma unroll
        for (int q = 0; q < 32; ++q) {
            unsigned int u = bgetu(src + q);
            dst[q] = __uint_as_float(u);
            ready &= (u != SENTU);
        }
        if (!ready) __builtin_amdgcn_s_sleep(2);
    } while (!ready);
}
__device__ __forceinline__ bool utry(const float* src, float* dst) {
    bool ready = true;
#pragma unroll
    for (int q = 0; q < 32; ++q) {
        unsigned int u = bgetu(src + q);
        dst[q] = __uint_as_float(u);
        ready &= (u != SENTU);
    }
    return ready;
}

// p for one chunk: 32 consecutive columns from even `base` (clamped), 16x float2 from LDS.
__device__ __forceinline__ void pload(const float* p_s, int base, float2* dst) {
#pragma unroll
    for (int q = 0; q < 16; ++q) {
        int idx = base + 2 * q;
        idx = idx < 0 ? 0 : (idx > NN - 2 ? NN - 2 : idx);
        dst[q] = *(const float2*)(p_s + idx);
    }
}

template<bool TOP, bool BOT, bool EDGE>
__device__ __forceinline__ void chunk_dual(
    int s0, int lane, bool l0,
    float tX0, float tX1, float tY0, float tY1,
    float& v0X, float& v1X, float& u1X, float& u2X, float upl,
    float& v0Y, float& v1Y, float& u1Y, float& u2Y,
    float& g2, float& g3, float& g4, float& bcin, float4& acc,
    const float* upc, const float2* pcX, const float2* pcY,
    float* __restrict__ bnd_my, float* __restrict__ outp)
{
#pragma unroll
    for (int u = 0; u < 32; ++u) {
        const int s  = s0 + u;
        const int jX = s - 2 * lane;
        const int jY = jX - YLAG;
        // shuffles issued now, consumed next step (latency off the chain)
        float nxtX = __shfl_up(v1X, 1);
        float nxtY = __shfl_up(v1Y, 1);
        float nbc  = __shfl(v1X, 63);      // X lane63 v1 (col s-127), lands in FIFO
        // ---- X row pair (rows 2l, 2l+1 of upper half) ----
        float aX, bX;
        if (TOP) {
            aX = l0 ? ((s == 0) ? 0.0f : BIGK) : u2X;
            bX = l0 ? BIGK : u1X;
        } else {
            float upj  = upc[u];
            float upjm = (u == 0) ? upl : upc[u - 1];
            aX = l0 ? upjm : u2X;
            bX = l0 ? upj  : u1X;
        }
        float pX = (u & 1) ? pcX[u >> 1].y : pcX[u >> 1].x;
        float dX0 = tX0 - pX;
        float valX0 = fmaf(dX0, dX0, softmin3s(aX, bX, v0X));
        float dX1 = tX1 - pX;
        float valX1 = fmaf(dX1, dX1, softmin3s(v0X, valX0, v1X));
        // ---- Y row pair (rows 2l, 2l+1 of lower half), fed by in-wave FIFO ----
        float aY = l0 ? g4 : u2Y;          // X row127 col jY-1
        float bY = l0 ? g3 : u1Y;          // X row127 col jY
        float pY = (u & 1) ? pcY[u >> 1].y : pcY[u >> 1].x;
        float dY0 = tY0 - pY;
        float valY0 = fmaf(dY0, dY0, softmin3s(aY, bY, v0Y));
        float dY1 = tY1 - pY;
        float valY1 = fmaf(dY1, dY1, softmin3s(v0Y, valY0, v1Y));
        if (EDGE) {
            bool vX = (unsigned)jX < (unsigned)NN;
            bool vY = (unsigned)jY < (unsigned)NN;
            valX0 = vX ? valX0 : BIGK;  valX1 = vX ? valX1 : BIGK;
            valY0 = vY ? valY0 : BIGK;  valY1 = vY ? valY1 : BIGK;
        }
        if (!BOT) {
            // Y lane63 publishes bottom row in float4 groups (jY ≡ u mod 4)
            switch (u & 3) {
                case 0: acc.x = valY1; break;
                case 1: acc.y = valY1; break;
                case 2: acc.z = valY1; break;
                case 3: acc.w = valY1; break;
            }
            if ((u & 3) == 3 && lane == 63) {
                int base = jY - 3;
                if (!EDGE || (unsigned)base <= (unsigned)(NN - 4)) {
                    bput(bnd_my + base + 0, acc.x);
                    bput(bnd_my + base + 1, acc.y);
                    bput(bnd_my + base + 2, acc.z);
                    bput(bnd_my + base + 3, acc.w);
                }
            }
        } else if (EDGE) {
            if (lane == 63 && s == OUTS) outp[0] = valY1 * IK2f;
        }
        v0X = valX0; v1X = valX1; u2X = u1X; u1X = nxtX;
        v0Y = valY0; v1Y = valY1; u2Y = u1Y; u1Y = nxtY;
        g4 = g3; g3 = g2; g2 = bcin; bcin = nbc;
    }
}

template<bool TOP, bool BOT>
__device__ __forceinline__ void chunk_iter(
    int ci, int lane, bool l0,
    float tX0, float tX1, float tY0, float tY1,
    float& v0X, float& v1X, float& u1X, float& u2X, float& upl,
    float& v0Y, float& v1Y, float& u1Y, float& u2Y,
    float& g2, float& g3, float& g4, float& bcin, float4& acc,
    float* upC, float* upN, float2* pXc, float2* pXn, float2* pYc, float2* pYn,
    bool& haveC, bool& haveN,
    const float* p_s, const float* __restrict__ bnd_up, float* __restrict__ bnd_my,
    float* __restrict__ outp)
{
    const int cs = 32 * ci;
    if (!TOP && cs < NN) {
        if (!haveC) upoll(bnd_up + cs, upC);                       // steady state: one pass
        if (cs + 32 < NN) haveN = utry(bnd_up + cs + 32, upN);     // prefetch next chunk
        else haveN = false;
    }
    if (ci + 1 < NCI) {
        pload(p_s, cs + 32 - 2 * lane, pXn);
        pload(p_s, cs + 32 - YLAG - 2 * lane, pYn);
    }

    const bool edge = (ci < 8) || (ci >= 128);
    if (edge) chunk_dual<TOP, BOT, true >(cs, lane, l0, tX0, tX1, tY0, tY1,
                                          v0X, v1X, u1X, u2X, upl, v0Y, v1Y, u1Y, u2Y,
                                          g2, g3, g4, bcin, acc, upC, pXc, pYc, bnd_my, outp);
    else      chunk_dual<TOP, BOT, false>(cs, lane, l0, tX0, tX1, tY0, tY1,
                                          v0X, v1X, u1X, u2X, upl, v0Y, v1Y, u1Y, u2Y,
                                          g2, g3, g4, bcin, acc, upC, pXc, pYc, bnd_my, outp);
    if (!TOP) upl = upC[31];
    haveC = false;
}

template<bool TOP, bool BOT>
__device__ void stripe(int b, int lane, const float* __restrict__ target,
                       const float* p_s, float* bnd, float* outp)
{
    const int rbase = 256 * b;
    const float tX0 = target[rbase + 2 * lane]           * SQK2f;
    const float tX1 = target[rbase + 2 * lane + 1]       * SQK2f;
    const float tY0 = target[rbase + 128 + 2 * lane]     * SQK2f;
    const float tY1 = target[rbase + 128 + 2 * lane + 1] * SQK2f;
    float* bnd_my = bnd + (size_t)b * NN;
    const float* bnd_up = bnd + (size_t)(b - 1) * NN;
    const bool l0 = (lane == 0);

    float v0X = BIGK, v1X = BIGK, u1X = BIGK, u2X = BIGK, upl = BIGK;
    float v0Y = BIGK, v1Y = BIGK, u1Y = BIGK, u2Y = BIGK;
    float g2 = BIGK, g3 = BIGK, g4 = BIGK, bcin = BIGK;
    float4 acc = {BIGK, BIGK, BIGK, BIGK};
    float upA[32], upB[32];
    float2 pXA[16], pXB[16], pYA[16], pYB[16];
    bool haveA = false, haveB = false;

    pload(p_s, -2 * lane, pXA);
    pload(p_s, -YLAG - 2 * lane, pYA);

    for (int cp = 0; cp < NCI / 2; ++cp) {
        chunk_iter<TOP, BOT>(2 * cp,     lane, l0, tX0, tX1, tY0, tY1,
                             v0X, v1X, u1X, u2X, upl, v0Y, v1Y, u1Y, u2Y,
                             g2, g3, g4, bcin, acc,
                             upA, upB, pXA, pXB, pYA, pYB, haveA, haveB,
                             p_s, bnd_up, bnd_my, outp);
        chunk_iter<TOP, BOT>(2 * cp + 1, lane, l0, tX0, tX1, tY0, tY1,
                             v0X, v1X, u1X, u2X, upl, v0Y, v1Y, u1Y, u2Y,
                             g2, g3, g4, bcin, acc,
                             upB, upA, pXB, pXA, pYB, pYA, haveB, haveA,
                             p_s, bnd_up, bnd_my, outp);
    }
}

__global__ __launch_bounds__(64, 1) void sdtw_pipe6(const float* __restrict__ pred,
                                                    const float* __restrict__ target,
                                                    float* __restrict__ out,
                                                    float* __restrict__ bnd)
{
    __shared__ float p_s[NN];
    const int lane = threadIdx.x;
    const int bid = blockIdx.x;
    const int b = (bid & 7) * 2 + (bid >> 3);   // pair stripe-neighbors per XCD
    for (int i = lane; i < NN; i += 64) p_s[i] = pred[i] * SQK2f;
    __syncthreads();
    if (b == 0)                stripe<true , false>(b, lane, target, p_s, bnd, out);
    else if (b == NBLK - 1)    stripe<false, true >(b, lane, target, p_s, bnd, out);
    else                       stripe<false, false>(b, lane, target, p_s, bnd, out);
}

extern "C" void kernel_launch(void* const* d_in, const int* in_sizes, int n_in,
                              void* d_out, int out_size, void* d_ws, size_t ws_size,
                              hipStream_t stream) {
    const float* pred   = (const float*)d_in[0];
    const float* target = (const float*)d_in[1];
    float* out = (float*)d_out;

    const size_t need = (size_t)NBLK * NN * sizeof(float);
    if (ws_size >= need) {
        float* bnd = (float*)d_ws;
        hipMemsetAsync(d_ws, 0xFF, need, stream);   // NaN-sentinel fill (value-carried readiness)
        sdtw_pipe6<<<dim3(NBLK), dim3(64), 0, stream>>>(pred, target, out, bnd);
    } else {
        dilate_sdtw<<<dim3(1), dim3(1024), 0, stream>>>(pred, target, out);
    }
}

// Round 8
// 935.800 us; speedup vs baseline: 1.7604x; 1.7604x over previous
//
#include <hip/hip_runtime.h>

#define NN    4096
#define BIGF  1e8f
// Scaled domain: R' = R * K2, K2 = (1/GAMMA)*log2(e).
// softmin'(a,b,c) = m - log2(exp2(m-a)+exp2(m-b)+exp2(m-c)); loss = R'/K2.
#define SQK2f 12.0112245225638540f    // sqrt(K2)
#define BIGK  1.4426950408889634e10f  // 1e8 * K2
#define IK2f  0.00693147180559945309f // 1/K2 = GAMMA*ln2
#define NBLK  32       // stripes of 128 rows (64 lanes x R=2)
#define NCI   132      // chunks of 32 steps: s = 0..4223
#define SKEW  72       // off(l) = (l&15) + 19*(l>>4); off(63) = 72
#define OUTS  4167     // 4095 + SKEW
#define SENTU 0xFFFFFFFFu   // NaN sentinel: DP values are never NaN

// ---------------- fallback: single-block diagonal kernel (verified r1) ----------------
__global__ __launch_bounds__(1024) void dilate_sdtw(const float* __restrict__ pred,
                                                    const float* __restrict__ target,
                                                    float* __restrict__ out) {
    __shared__ float t_s[NN];
    __shared__ float p_s[NN];
    __shared__ float bufA[NN];
    __shared__ float bufB[NN];
    __shared__ float bufC[NN];
    const int tid = threadIdx.x;
    for (int i = tid; i < NN; i += 1024) {
        t_s[i] = target[i]; p_s[i] = pred[i];
        bufA[i] = BIGF; bufB[i] = BIGF; bufC[i] = BIGF;
    }
    __syncthreads();
    float* r2 = bufA; float* r1 = bufB; float* rn = bufC;
    for (int k = 0; k < 2 * NN - 1; ++k) {
        int ilo = k - (NN - 1); if (ilo < 0) ilo = 0;
        int ihi = (k < NN - 1) ? k : (NN - 1);
        for (int i = ilo + tid; i <= ihi; i += 1024) {
            const int j = k - i;
            float diff = t_s[i] - p_s[j];
            float d = diff * diff;
            float a = (i >= 1 && j >= 1) ? r2[i - 1] : ((k == 0) ? 0.0f : BIGF);
            float b = (i >= 1) ? r1[i - 1] : BIGF;
            float c = (j >= 1) ? r1[i] : BIGF;
            float m = fminf(a, fminf(b, c));
            float s = __expf((m - a) * 100.0f) + __expf((m - b) * 100.0f) + __expf((m - c) * 100.0f);
            rn[i] = d + m - 0.01f * __logf(s);
        }
        __syncthreads();
        float* tmp = r2; r2 = r1; r1 = rn; rn = tmp;
    }
    if (tid == 0) out[0] = r1[NN - 1];
}

// ---- R=2 lane-systolic, DPP intra-group sigma=1 (skew 72), async-split sync ----

__device__ __forceinline__ float softmin3s(float a, float b, float c) {
    float m = fminf(a, fminf(b, c));
    float e = __builtin_amdgcn_exp2f(m - a)
            + __builtin_amdgcn_exp2f(m - b)
            + __builtin_amdgcn_exp2f(m - c);
    return m - __builtin_amdgcn_logf(e);   // logf builtin = log2
}

__device__ __forceinline__ void bput(float* p, float v) {
    __hip_atomic_store((unsigned int*)p, __float_as_uint(v),
                       __ATOMIC_RELAXED, __HIP_MEMORY_SCOPE_AGENT);
}
__device__ __forceinline__ unsigned int bgetu(const float* p) {
    return __hip_atomic_load((const unsigned int*)p,
                             __ATOMIC_RELAXED, __HIP_MEMORY_SCOPE_AGENT);
}

// issue 32 relaxed loads into regs; NO use -> compiler defers the vmcnt wait
__device__ __forceinline__ void uissue(const float* src, float* dst) {
#pragma unroll
    for (int q = 0; q < 32; ++q) dst[q] = __uint_as_float(bgetu(src + q));
}
// forces the wait (32 steps after issue in the fast path -> latency hidden)
__device__ __forceinline__ bool uvalid(const float* dst) {
    bool ok = true;
#pragma unroll
    for (int q = 0; q < 32; ++q) ok &= (__float_as_uint(dst[q]) != SENTU);
    return ok;
}
__device__ __forceinline__ void upoll(const float* src, float* dst) {
    for (;;) {
        uissue(src, dst);
        if (uvalid(dst)) return;
        __builtin_amdgcn_s_sleep(1);
    }
}

// p for one chunk: 32 columns from per-lane base (clamped), scalar LDS reads
__device__ __forceinline__ void pload(const float* p_s, int base, float* dst) {
#pragma unroll
    for (int q = 0; q < 32; ++q) {
        int idx = base + q;
        idx = idx < 0 ? 0 : (idx > NN - 1 ? NN - 1 : idx);
        dst[q] = p_s[idx];
    }
}

template<bool TOP, bool BOT, bool EDGE>
__device__ __forceinline__ void chunk32(
    int cs, int lane, int off, bool l0, float t0, float t1,
    float& v0, float& v1, float& u2, float& sh1, float& sh2, float& sh3, float upl,
    float4& acc, const float* upc, const float* pc,
    float* __restrict__ bnd_my, float* __restrict__ outp)
{
#pragma unroll
    for (int u = 0; u < 32; ++u) {
        const int s = cs + u;
        const int j = s - off;
        // u1 for THIS step: intra-group neighbor via DPP row_shr:1 (sigma=1);
        // group-boundary lanes (l%16==0) patched from 3-step-old shuffle (old operand).
        float u1 = __int_as_float(__builtin_amdgcn_update_dpp(
            __float_as_int(sh3), __float_as_int(v1), 0x111, 0xF, 0xF, false));
        // issue shuffle now (reads v1 of step s-1), consumed as sh3 at step s+3
        float shN = __shfl_up(v1, 1);
        float a, b;
        if (TOP) {
            a = l0 ? ((s == 0) ? 0.0f : BIGK) : u2;
            b = l0 ? BIGK : u1;
        } else {
            float upj  = upc[u];
            float upjm = (u == 0) ? upl : upc[u - 1];
            a = l0 ? upjm : u2;
            b = l0 ? upj  : u1;
        }
        float pj = pc[u];
        float d0 = t0 - pj;
        float val0 = fmaf(d0, d0, softmin3s(a, b, v0));      // row 2l, col j
        float d1 = t1 - pj;
        float val1 = fmaf(d1, d1, softmin3s(v0, val0, v1));  // row 2l+1, col j
        if (EDGE) {
            bool vj = (unsigned)j < (unsigned)NN;
            val0 = vj ? val0 : BIGK;
            val1 = vj ? val1 : BIGK;
        }
        if (!BOT) {
            // lane63 (off=72, 72%4==0): j%4 == u%4. collect 4, publish at u%4==3.
            switch (u & 3) {
                case 0: acc.x = val1; break;
                case 1: acc.y = val1; break;
                case 2: acc.z = val1; break;
                case 3: acc.w = val1; break;
            }
            if ((u & 3) == 3) {
                int base = j - 3;
                if (lane == 63 && (!EDGE || (unsigned)base <= (unsigned)(NN - 4))) {
                    bput(bnd_my + base + 0, acc.x);
                    bput(bnd_my + base + 1, acc.y);
                    bput(bnd_my + base + 2, acc.z);
                    bput(bnd_my + base + 3, acc.w);
                }
            }
        } else if (EDGE) {
            if (lane == 63 && s == OUTS) outp[0] = val1 * IK2f;
        }
        v0 = val0; v1 = val1; u2 = u1;
        sh3 = sh2; sh2 = sh1; sh1 = shN;
    }
}

template<bool TOP, bool BOT>
__device__ __forceinline__ void chunk_iter(
    int ci, int lane, int off, bool l0, float t0, float t1,
    float& v0, float& v1, float& u2, float& sh1, float& sh2, float& sh3, float& upl,
    float4& acc,
    float* upC, float* upN, float* pcC, float* pcN,
    const float* p_s, const float* __restrict__ bnd_up, float* __restrict__ bnd_my,
    float* __restrict__ outp)
{
    const int cs = 32 * ci;
    if (!TOP && cs < NN) {
        if (!uvalid(upC)) upoll(bnd_up + cs, upC);      // fast path: issued last chunk
        if (cs + 32 < NN) uissue(bnd_up + cs + 32, upN); // issue for next chunk, no wait
    }
    if (ci + 1 < NCI) pload(p_s, cs + 32 - off, pcN);

    const bool edge = (ci < 4) || (ci >= 128);
    if (edge) chunk32<TOP, BOT, true >(cs, lane, off, l0, t0, t1, v0, v1, u2,
                                       sh1, sh2, sh3, upl, acc, upC, pcC, bnd_my, outp);
    else      chunk32<TOP, BOT, false>(cs, lane, off, l0, t0, t1, v0, v1, u2,
                                       sh1, sh2, sh3, upl, acc, upC, pcC, bnd_my, outp);
    if (!TOP) upl = upC[31];
}

template<bool TOP, bool BOT>
__device__ void stripe(int b, int lane, const float* __restrict__ target,
                       const float* p_s, float* bnd, float* outp)
{
    const int off = (lane & 15) + 19 * (lane >> 4);     // intra sigma=1, group gap 4
    const float t0 = target[128 * b + 2 * lane]     * SQK2f;   // FIXED: 128 rows/stripe
    const float t1 = target[128 * b + 2 * lane + 1] * SQK2f;
    float* bnd_my = bnd + (size_t)b * NN;
    const float* bnd_up = bnd + (size_t)(b - 1) * NN;
    const bool l0 = (lane == 0);

    float v0 = BIGK, v1 = BIGK, u2 = BIGK, upl = BIGK;
    float sh1 = BIGK, sh2 = BIGK, sh3 = BIGK;
    float4 acc = {BIGK, BIGK, BIGK, BIGK};
    float upA[32], upB[32];
    float pcA[32], pcB[32];

    pload(p_s, -off, pcA);
    if (!TOP) uissue(bnd_up, upA);   // prologue issue for chunk 0

    for (int cp = 0; cp < NCI / 2; ++cp) {
        chunk_iter<TOP, BOT>(2 * cp,     lane, off, l0, t0, t1, v0, v1, u2,
                             sh1, sh2, sh3, upl, acc,
                             upA, upB, pcA, pcB, p_s, bnd_up, bnd_my, outp);
        chunk_iter<TOP, BOT>(2 * cp + 1, lane, off, l0, t0, t1, v0, v1, u2,
                             sh1, sh2, sh3, upl, acc,
                             upB, upA, pcB, pcA, p_s, bnd_up, bnd_my, outp);
    }
}

__global__ __launch_bounds__(64, 1) void sdtw_pipe8(const float* __restrict__ pred,
                                                    const float* __restrict__ target,
                                                    float* __restrict__ out,
                                                    float* __restrict__ bnd)
{
    __shared__ float p_s[NN];
    const int lane = threadIdx.x;
    const int bid = blockIdx.x;
    const int b = (bid & 7) * 4 + (bid >> 3);   // group stripe-neighbors per XCD
    for (int i = lane; i < NN; i += 64) p_s[i] = pred[i] * SQK2f;
    __syncthreads();
    if (b == 0)                stripe<true , false>(b, lane, target, p_s, bnd, out);
    else if (b == NBLK - 1)    stripe<false, true >(b, lane, target, p_s, bnd, out);
    else                       stripe<false, false>(b, lane, target, p_s, bnd, out);
}

extern "C" void kernel_launch(void* const* d_in, const int* in_sizes, int n_in,
                              void* d_out, int out_size, void* d_ws, size_t ws_size,
                              hipStream_t stream) {
    const float* pred   = (const float*)d_in[0];
    const float* target = (const float*)d_in[1];
    float* out = (float*)d_out;

    const size_t need = (size_t)NBLK * NN * sizeof(float);
    if (ws_size >= need) {
        float* bnd = (float*)d_ws;
        hipMemsetAsync(d_ws, 0xFF, need, stream);   // NaN-sentinel fill (value-carried readiness)
        sdtw_pipe8<<<dim3(NBLK), dim3(64), 0, stream>>>(pred, target, out, bnd);
    } else {
        dilate_sdtw<<<dim3(1), dim3(1024), 0, stream>>>(pred, target, out);
    }
}

// Round 9
// 858.308 us; speedup vs baseline: 1.9193x; 1.0903x over previous
//
#include <hip/hip_runtime.h>

#define NN    4096
#define BIGF  1e8f
// Scaled domain: R' = R * K2, K2 = (1/GAMMA)*log2(e).
// softmin'(a,b,c) = m - log2(exp2(m-a)+exp2(m-b)+exp2(m-c)); loss = R'/K2.
#define SQK2f 12.0112245225638540f    // sqrt(K2)
#define BIGK  1.4426950408889634e10f  // 1e8 * K2
#define IK2f  0.00693147180559945309f // 1/K2 = GAMMA*ln2
#define NBLK  32       // stripes of 128 rows (64 lanes x R=2)
#define NCI   130      // chunks of 32 steps: s = 0..4159
#define OUTS  4158     // lane63: j = 4095 at s = 4095 + 63
#define SENTU 0xFFFFFFFFu   // NaN sentinel: DP values are never NaN

// ---------------- fallback: single-block diagonal kernel (verified r1) ----------------
__global__ __launch_bounds__(1024) void dilate_sdtw(const float* __restrict__ pred,
                                                    const float* __restrict__ target,
                                                    float* __restrict__ out) {
    __shared__ float t_s[NN];
    __shared__ float p_s[NN];
    __shared__ float bufA[NN];
    __shared__ float bufB[NN];
    __shared__ float bufC[NN];
    const int tid = threadIdx.x;
    for (int i = tid; i < NN; i += 1024) {
        t_s[i] = target[i]; p_s[i] = pred[i];
        bufA[i] = BIGF; bufB[i] = BIGF; bufC[i] = BIGF;
    }
    __syncthreads();
    float* r2 = bufA; float* r1 = bufB; float* rn = bufC;
    for (int k = 0; k < 2 * NN - 1; ++k) {
        int ilo = k - (NN - 1); if (ilo < 0) ilo = 0;
        int ihi = (k < NN - 1) ? k : (NN - 1);
        for (int i = ilo + tid; i <= ihi; i += 1024) {
            const int j = k - i;
            float diff = t_s[i] - p_s[j];
            float d = diff * diff;
            float a = (i >= 1 && j >= 1) ? r2[i - 1] : ((k == 0) ? 0.0f : BIGF);
            float b = (i >= 1) ? r1[i - 1] : BIGF;
            float c = (j >= 1) ? r1[i] : BIGF;
            float m = fminf(a, fminf(b, c));
            float s = __expf((m - a) * 100.0f) + __expf((m - b) * 100.0f) + __expf((m - c) * 100.0f);
            rn[i] = d + m - 0.01f * __logf(s);
        }
        __syncthreads();
        float* tmp = r2; r2 = r1; r1 = rn; rn = tmp;
    }
    if (tid == 0) out[0] = r1[NN - 1];
}

// ---- R=2 lane-systolic, sigma=1 all-VALU neighbor (DPP row_shr + row_bcast15), async sync ----

__device__ __forceinline__ float softmin3s(float a, float b, float c) {
    float m = fminf(a, fminf(b, c));
    float e = __builtin_amdgcn_exp2f(m - a)
            + __builtin_amdgcn_exp2f(m - b)
            + __builtin_amdgcn_exp2f(m - c);
    return m - __builtin_amdgcn_logf(e);   // logf builtin = log2
}

// lane l  <-  lane l-1, across the whole wave, pure VALU:
// row_shr:1 covers lanes 1-15 of each 16-row; row_bcast:15 covers lanes 16/32/48.
__device__ __forceinline__ float nbr1(float v, bool bsel) {
    int iv = __float_as_int(v);
    float a = __int_as_float(__builtin_amdgcn_update_dpp(iv, iv, 0x111, 0xF, 0xF, false)); // row_shr:1
    float b = __int_as_float(__builtin_amdgcn_update_dpp(iv, iv, 0x142, 0xF, 0xF, false)); // row_bcast:15
    return bsel ? b : a;
}

__device__ __forceinline__ void bput(float* p, float v) {
    __hip_atomic_store((unsigned int*)p, __float_as_uint(v),
                       __ATOMIC_RELAXED, __HIP_MEMORY_SCOPE_AGENT);
}
__device__ __forceinline__ unsigned int bgetu(const float* p) {
    return __hip_atomic_load((const unsigned int*)p,
                             __ATOMIC_RELAXED, __HIP_MEMORY_SCOPE_AGENT);
}

// issue 32 relaxed loads into regs; no use -> wait deferred to uvalid
__device__ __forceinline__ void uissue(const float* src, float* dst) {
#pragma unroll
    for (int q = 0; q < 32; ++q) dst[q] = __uint_as_float(bgetu(src + q));
}
__device__ __forceinline__ bool uvalid(const float* dst) {
    bool ok = true;
#pragma unroll
    for (int q = 0; q < 32; ++q) ok &= (__float_as_uint(dst[q]) != SENTU);
    return ok;
}
__device__ __forceinline__ void upoll(const float* src, float* dst) {
    for (;;) {
        uissue(src, dst);
        if (uvalid(dst)) return;
        __builtin_amdgcn_s_sleep(1);
    }
}

// p for one chunk: 32 columns from per-lane base (clamped), scalar LDS reads
__device__ __forceinline__ void pload(const float* p_s, int base, float* dst) {
#pragma unroll
    for (int q = 0; q < 32; ++q) {
        int idx = base + q;
        idx = idx < 0 ? 0 : (idx > NN - 1 ? NN - 1 : idx);
        dst[q] = p_s[idx];
    }
}

template<bool TOP, bool BOT, bool EDGE>
__device__ __forceinline__ void chunk32(
    int cs, int lane, bool l0, bool bsel, float t0, float t1,
    float& v0, float& v1, float& u1, float& u2, float upl,
    float4& acc, const float* upc, const float* pc,
    float* __restrict__ bnd_my, float* __restrict__ outp)
{
#pragma unroll
    for (int u = 0; u < 32; ++u) {
        const int s = cs + u;
        const int j = s - lane;          // off(l) = l, skew 63
        float a, b;
        if (TOP) {
            a = l0 ? ((s == 0) ? 0.0f : BIGK) : u2;
            b = l0 ? BIGK : u1;
        } else {
            float upj  = upc[u];
            float upjm = (u == 0) ? upl : upc[u - 1];
            a = l0 ? upjm : u2;
            b = l0 ? upj  : u1;
        }
        float pj = pc[u];
        float d0 = t0 - pj;
        float val0 = fmaf(d0, d0, softmin3s(a, b, v0));      // row 2l, col j
        float d1 = t1 - pj;
        float val1 = fmaf(d1, d1, softmin3s(v0, val0, v1));  // row 2l+1, col j
        if (EDGE) {
            bool vj = (unsigned)j < (unsigned)NN;
            val0 = vj ? val0 : BIGK;
            val1 = vj ? val1 : BIGK;
        }
        if (!BOT) {
            // lane63: j = s-63, j%4 == (u+1)%4. collect 4 cols, publish when j%4==3 (u%4==2)
            switch ((u + 1) & 3) {
                case 0: acc.x = val1; break;
                case 1: acc.y = val1; break;
                case 2: acc.z = val1; break;
                case 3: acc.w = val1; break;
            }
            if ((u & 3) == 2) {
                int base = j - 3;
                if (lane == 63 && (!EDGE || (unsigned)base <= (unsigned)(NN - 4))) {
                    bput(bnd_my + base + 0, acc.x);
                    bput(bnd_my + base + 1, acc.y);
                    bput(bnd_my + base + 2, acc.z);
                    bput(bnd_my + base + 3, acc.w);
                }
            }
        } else if (EDGE) {
            if (lane == 63 && s == OUTS) outp[0] = val1 * IK2f;
        }
        v0 = val0; v1 = val1;
        u2 = u1;
        u1 = nbr1(val1, bsel);   // neighbor's v1 @ s, consumed at s+1 (pure VALU)
    }
}

template<bool TOP, bool BOT>
__device__ __forceinline__ void chunk_iter(
    int ci, int lane, bool l0, bool bsel, float t0, float t1,
    float& v0, float& v1, float& u1, float& u2, float& upl,
    float4& acc,
    float* upC, float* upN, float* pcC, float* pcN,
    const float* p_s, const float* __restrict__ bnd_up, float* __restrict__ bnd_my,
    float* __restrict__ outp)
{
    const int cs = 32 * ci;
    if (!TOP && cs < NN) {
        if (!uvalid(upC)) upoll(bnd_up + cs, upC);       // fast path: issued last chunk
        if (cs + 32 < NN) uissue(bnd_up + cs + 32, upN); // issue for next chunk, no wait
    }
    if (ci + 1 < NCI) pload(p_s, cs + 32 - lane, pcN);

    const bool edge = (ci < 2) || (ci >= 128);
    if (edge) chunk32<TOP, BOT, true >(cs, lane, l0, bsel, t0, t1, v0, v1, u1, u2,
                                       upl, acc, upC, pcC, bnd_my, outp);
    else      chunk32<TOP, BOT, false>(cs, lane, l0, bsel, t0, t1, v0, v1, u1, u2,
                                       upl, acc, upC, pcC, bnd_my, outp);
    if (!TOP) upl = upC[31];
}

template<bool TOP, bool BOT>
__device__ void stripe(int b, int lane, const float* __restrict__ target,
                       const float* p_s, float* bnd, float* outp)
{
    const float t0 = target[128 * b + 2 * lane]     * SQK2f;
    const float t1 = target[128 * b + 2 * lane + 1] * SQK2f;
    float* bnd_my = bnd + (size_t)b * NN;
    const float* bnd_up = bnd + (size_t)(b - 1) * NN;
    const bool l0 = (lane == 0);
    const bool bsel = (lane != 0) && ((lane & 15) == 0);   // lanes 16/32/48: row-crossing

    float v0 = BIGK, v1 = BIGK, u1 = BIGK, u2 = BIGK, upl = BIGK;
    float4 acc = {BIGK, BIGK, BIGK, BIGK};
    float upA[32], upB[32];
    float pcA[32], pcB[32];

    pload(p_s, -lane, pcA);
    if (!TOP) uissue(bnd_up, upA);   // prologue issue for chunk 0

    for (int cp = 0; cp < NCI / 2; ++cp) {
        chunk_iter<TOP, BOT>(2 * cp,     lane, l0, bsel, t0, t1, v0, v1, u1, u2, upl, acc,
                             upA, upB, pcA, pcB, p_s, bnd_up, bnd_my, outp);
        chunk_iter<TOP, BOT>(2 * cp + 1, lane, l0, bsel, t0, t1, v0, v1, u1, u2, upl, acc,
                             upB, upA, pcB, pcA, p_s, bnd_up, bnd_my, outp);
    }
}

__global__ __launch_bounds__(64, 1) void sdtw_pipe9(const float* __restrict__ pred,
                                                    const float* __restrict__ target,
                                                    float* __restrict__ out,
                                                    float* __restrict__ bnd)
{
    __shared__ float p_s[NN];
    const int lane = threadIdx.x;
    const int bid = blockIdx.x;
    const int b = (bid & 7) * 4 + (bid >> 3);   // group stripe-neighbors per XCD
    for (int i = lane; i < NN; i += 64) p_s[i] = pred[i] * SQK2f;
    __syncthreads();
    if (b == 0)                stripe<true , false>(b, lane, target, p_s, bnd, out);
    else if (b == NBLK - 1)    stripe<false, true >(b, lane, target, p_s, bnd, out);
    else                       stripe<false, false>(b, lane, target, p_s, bnd, out);
}

extern "C" void kernel_launch(void* const* d_in, const int* in_sizes, int n_in,
                              void* d_out, int out_size, void* d_ws, size_t ws_size,
                              hipStream_t stream) {
    const float* pred   = (const float*)d_in[0];
    const float* target = (const float*)d_in[1];
    float* out = (float*)d_out;

    const size_t need = (size_t)NBLK * NN * sizeof(float);
    if (ws_size >= need) {
        float* bnd = (float*)d_ws;
        hipMemsetAsync(d_ws, 0xFF, need, stream);   // NaN-sentinel fill (value-carried readiness)
        sdtw_pipe9<<<dim3(NBLK), dim3(64), 0, stream>>>(pred, target, out, bnd);
    } else {
        dilate_sdtw<<<dim3(1), dim3(1024), 0, stream>>>(pred, target, out);
    }
}